// Round 1
// baseline (123.109 us; speedup 1.0000x reference)
//
#include <hip/hip_runtime.h>

// Problem constants (match reference)
constexpr int B = 16;
constexpr int N = 100000;
constexpr int E = 10;
constexpr int D = 3;

// Kernel 1: diff = coord2 - coord1, float4 vectorized.
__global__ __launch_bounds__(256) void diff_kernel(const float* __restrict__ c1,
                                                   const float* __restrict__ c2,
                                                   float* __restrict__ diff,
                                                   int n4) {
    int i = blockIdx.x * blockDim.x + threadIdx.x;
    if (i < n4) {
        float4 a = reinterpret_cast<const float4*>(c1)[i];
        float4 b = reinterpret_cast<const float4*>(c2)[i];
        float4 d;
        d.x = b.x - a.x; d.y = b.y - a.y; d.z = b.z - a.z; d.w = b.w - a.w;
        reinterpret_cast<float4*>(diff)[i] = d;
    }
}

// Kernel 2: per-node laplacian-of-diff squared, reduce, atomicAdd.
__global__ __launch_bounds__(256) void loss_kernel(const float* __restrict__ diff,
                                                   const int* __restrict__ A,
                                                   float* __restrict__ out) {
    // XCD-aware swizzle: gridDim.x is a multiple of 8; XCD x (bid%8) gets a
    // contiguous chunk of nodes -> per-XCD L2 gather working set ~2 batches.
    int per = gridDim.x >> 3;
    int w = (blockIdx.x & 7) * per + (blockIdx.x >> 3);
    int node = w * blockDim.x + threadIdx.x;

    float sq = 0.0f;
    if (node < B * N) {
        int b = node / N;          // compiler magic-mul
        int n = node - b * N;
        const float* db = diff + (size_t)b * N * D;

        // A_list row: 10 consecutive ints, 40B = 8-byte aligned -> int2 loads
        const int2* a2 = reinterpret_cast<const int2*>(A + (size_t)node * E);
        float sx = 0.f, sy = 0.f, sz = 0.f;
        int cnt = 0;
        #pragma unroll
        for (int e2 = 0; e2 < E / 2; ++e2) {
            int2 p = a2[e2];
            if (p.x >= 0) {
                const float* q = db + (size_t)p.x * D;
                sx += q[0]; sy += q[1]; sz += q[2];
                ++cnt;
            }
            if (p.y >= 0) {
                const float* q = db + (size_t)p.y * D;
                sx += q[0]; sy += q[1]; sz += q[2];
                ++cnt;
            }
        }
        float inv = 1.0f / (float)cnt;   // cnt >= 1 (slot 0 always valid)
        const float* own = db + (size_t)n * D;
        float lx = own[0] - sx * inv;
        float ly = own[1] - sy * inv;
        float lz = own[2] - sz * inv;
        sq = lx * lx + ly * ly + lz * lz;
    }

    // wave(64) reduce then cross-wave via LDS
    #pragma unroll
    for (int off = 32; off > 0; off >>= 1)
        sq += __shfl_down(sq, off, 64);

    __shared__ float wsum[4];
    int lane = threadIdx.x & 63;
    int wid = threadIdx.x >> 6;
    if (lane == 0) wsum[wid] = sq;
    __syncthreads();
    if (threadIdx.x == 0) {
        float t = (wsum[0] + wsum[1]) + (wsum[2] + wsum[3]);
        // loss = sum /(B*N*D) * N = sum/(B*D)
        atomicAdd(out, t * (1.0f / (float)(B * D)));
    }
}

extern "C" void kernel_launch(void* const* d_in, const int* in_sizes, int n_in,
                              void* d_out, int out_size, void* d_ws, size_t ws_size,
                              hipStream_t stream) {
    const float* coord1 = (const float*)d_in[0];
    const float* coord2 = (const float*)d_in[1];
    const int* A_list = (const int*)d_in[2];
    float* out = (float*)d_out;
    float* diff = (float*)d_ws;   // needs B*N*D*4 = 19.2 MB

    // zero the scalar accumulator (d_out is poisoned before timing)
    hipMemsetAsync(out, 0, sizeof(float), stream);

    int total_f = B * N * D;          // 4.8M floats
    int n4 = total_f / 4;             // 1.2M float4s (divisible)
    diff_kernel<<<(n4 + 255) / 256, 256, 0, stream>>>(coord1, coord2, diff, n4);

    int nodes = B * N;                          // 1.6M
    int nblk = (nodes + 255) / 256;             // 6250
    nblk = (nblk + 7) & ~7;                     // pad to multiple of 8 -> 6256
    loss_kernel<<<nblk, 256, 0, stream>>>(diff, A_list, out);
}

// Round 2
// 112.176 us; speedup vs baseline: 1.0975x; 1.0975x over previous
//
#include <hip/hip_runtime.h>

// Problem constants (match reference)
constexpr int B = 16;
constexpr int N = 100000;
constexpr int E = 10;
constexpr int D = 3;

// ---------------------------------------------------------------------------
// diff kernels: diff = coord2 - coord1
// Padded variant writes float4 records (xyz + 0 pad) for 1-load gathers.
// ---------------------------------------------------------------------------
__global__ __launch_bounds__(256) void diff4_kernel(const float* __restrict__ c1,
                                                    const float* __restrict__ c2,
                                                    float4* __restrict__ diffp,
                                                    int nquad) {  // nquad = B*N/4
    int i = blockIdx.x * blockDim.x + threadIdx.x;
    if (i >= nquad) return;
    // thread i handles nodes 4i..4i+3 -> 12 contiguous floats in, 4 float4 out
    const float4* a4 = reinterpret_cast<const float4*>(c1) + (size_t)i * 3;
    const float4* b4 = reinterpret_cast<const float4*>(c2) + (size_t)i * 3;
    float4 a0 = a4[0], a1 = a4[1], a2 = a4[2];
    float4 b0 = b4[0], b1 = b4[1], b2 = b4[2];
    float d[12];
    d[0] = b0.x - a0.x; d[1] = b0.y - a0.y; d[2] = b0.z - a0.z; d[3] = b0.w - a0.w;
    d[4] = b1.x - a1.x; d[5] = b1.y - a1.y; d[6] = b1.z - a1.z; d[7] = b1.w - a1.w;
    d[8] = b2.x - a2.x; d[9] = b2.y - a2.y; d[10] = b2.z - a2.z; d[11] = b2.w - a2.w;
    float4* o = diffp + (size_t)i * 4;
    o[0] = make_float4(d[0], d[1], d[2], 0.f);
    o[1] = make_float4(d[3], d[4], d[5], 0.f);
    o[2] = make_float4(d[6], d[7], d[8], 0.f);
    o[3] = make_float4(d[9], d[10], d[11], 0.f);
}

__global__ __launch_bounds__(256) void diff_kernel(const float* __restrict__ c1,
                                                   const float* __restrict__ c2,
                                                   float* __restrict__ diff,
                                                   int n4) {
    int i = blockIdx.x * blockDim.x + threadIdx.x;
    if (i < n4) {
        float4 a = reinterpret_cast<const float4*>(c1)[i];
        float4 b = reinterpret_cast<const float4*>(c2)[i];
        reinterpret_cast<float4*>(diff)[i] =
            make_float4(b.x - a.x, b.y - a.y, b.z - a.z, b.w - a.w);
    }
}

// ---------------------------------------------------------------------------
// loss kernel: per-node laplacian-of-diff squared -> block reduce -> atomicAdd
// All gathers unconditional (invalid -> index 0, masked to 0.0) so the
// compiler can put every load in flight before the first waitcnt.
// ---------------------------------------------------------------------------
template <bool PAD4>
__global__ __launch_bounds__(256) void loss_kernel(const float* __restrict__ diff,
                                                   const int* __restrict__ A,
                                                   float* __restrict__ out) {
    // XCD-aware swizzle: contiguous node chunk per XCD -> gather set fits L2
    int per = gridDim.x >> 3;
    int w = (blockIdx.x & 7) * per + (blockIdx.x >> 3);
    int node = w * blockDim.x + threadIdx.x;

    float sq = 0.0f;
    if (node < B * N) {
        int b = node / N;  // magic-mul
        // A_list row: 10 ints, 40B, 8B-aligned -> int4,int4,int2
        const int* arow = A + (size_t)node * E;
        int4 p0 = *reinterpret_cast<const int4*>(arow);
        int4 p1 = *reinterpret_cast<const int4*>(arow + 4);
        int2 p2 = *reinterpret_cast<const int2*>(arow + 8);
        int idx[E] = {p0.x, p0.y, p0.z, p0.w, p1.x, p1.y, p1.z, p1.w, p2.x, p2.y};

        float sx = 0.f, sy = 0.f, sz = 0.f;
        float fcnt = 0.f;
        float lx, ly, lz;

        if (PAD4) {
            const float4* db = reinterpret_cast<const float4*>(diff) + (size_t)b * N;
            float4 v[E];
            float m[E];
            #pragma unroll
            for (int e = 0; e < E; ++e) {
                int ix = idx[e];
                m[e] = (ix >= 0) ? 1.0f : 0.0f;
                v[e] = db[ix >= 0 ? ix : 0];   // independent dwordx4 loads
            }
            float4 own = db[node - b * N];
            #pragma unroll
            for (int e = 0; e < E; ++e) {
                sx = fmaf(v[e].x, m[e], sx);
                sy = fmaf(v[e].y, m[e], sy);
                sz = fmaf(v[e].z, m[e], sz);
                fcnt += m[e];
            }
            float inv = 1.0f / fcnt;           // fcnt >= 1 (slot 0 valid)
            lx = own.x - sx * inv;
            ly = own.y - sy * inv;
            lz = own.z - sz * inv;
        } else {
            const float* db = diff + (size_t)b * N * D;
            float vx[E], vy[E], vz[E], m[E];
            #pragma unroll
            for (int e = 0; e < E; ++e) {
                int ix = idx[e];
                m[e] = (ix >= 0) ? 1.0f : 0.0f;
                const float* q = db + (size_t)(ix >= 0 ? ix : 0) * D;
                float2 xy = *reinterpret_cast<const float2*>(q);  // may straddle; ok
                vx[e] = xy.x; vy[e] = xy.y; vz[e] = q[2];
            }
            int n = node - b * N;
            const float* ownp = db + (size_t)n * D;
            float ox = ownp[0], oy = ownp[1], oz = ownp[2];
            #pragma unroll
            for (int e = 0; e < E; ++e) {
                sx = fmaf(vx[e], m[e], sx);
                sy = fmaf(vy[e], m[e], sy);
                sz = fmaf(vz[e], m[e], sz);
                fcnt += m[e];
            }
            float inv = 1.0f / fcnt;
            lx = ox - sx * inv;
            ly = oy - sy * inv;
            lz = oz - sz * inv;
        }
        sq = lx * lx + ly * ly + lz * lz;
    }

    // wave(64) reduce then cross-wave via LDS
    #pragma unroll
    for (int off = 32; off > 0; off >>= 1)
        sq += __shfl_down(sq, off, 64);

    __shared__ float wsum[4];
    int lane = threadIdx.x & 63;
    int wid = threadIdx.x >> 6;
    if (lane == 0) wsum[wid] = sq;
    __syncthreads();
    if (threadIdx.x == 0) {
        float t = (wsum[0] + wsum[1]) + (wsum[2] + wsum[3]);
        // loss = sum/(B*N*D) * N = sum/(B*D)
        atomicAdd(out, t * (1.0f / (float)(B * D)));
    }
}

extern "C" void kernel_launch(void* const* d_in, const int* in_sizes, int n_in,
                              void* d_out, int out_size, void* d_ws, size_t ws_size,
                              hipStream_t stream) {
    const float* coord1 = (const float*)d_in[0];
    const float* coord2 = (const float*)d_in[1];
    const int* A_list = (const int*)d_in[2];
    float* out = (float*)d_out;
    float* diff = (float*)d_ws;

    hipMemsetAsync(out, 0, sizeof(float), stream);

    const size_t pad4_bytes = (size_t)B * N * 4 * sizeof(float);  // 25.6 MB
    const bool pad4 = ws_size >= pad4_bytes;

    int nodes = B * N;  // 1.6M
    if (pad4) {
        int nquad = nodes / 4;  // 400000
        diff4_kernel<<<(nquad + 255) / 256, 256, 0, stream>>>(
            coord1, coord2, (float4*)diff, nquad);
    } else {
        int n4 = nodes * D / 4;  // 1.2M
        diff_kernel<<<(n4 + 255) / 256, 256, 0, stream>>>(coord1, coord2, diff, n4);
    }

    int nblk = (nodes + 255) / 256;   // 6250
    nblk = (nblk + 7) & ~7;           // multiple of 8 for XCD swizzle
    if (pad4)
        loss_kernel<true><<<nblk, 256, 0, stream>>>(diff, A_list, out);
    else
        loss_kernel<false><<<nblk, 256, 0, stream>>>(diff, A_list, out);
}